// Round 19
// baseline (295.828 us; speedup 1.0000x reference)
//
#include <hip/hip_runtime.h>
#include <hip/hip_bf16.h>

// Connected filter:
//   vals[i] = sigmoid(clamp(100*(attrs[i]·w + b), ±12)) * residue[i]
//   cum[i]  = sum of vals along parent chain from i (dummy N terminates)
//   out[p]  = cum[pixel_to_node[p]]
// parent[i] < i (topological), parent[N] = N (dummy, val 0).
//
// Pipeline (serial — R8/R9/R14: NO fusion of saturating phases pays):
//   gate+pack | count -> scanA/B/C -> walks L0/L1/L2/L3 -> scatter -> gather
//   (LDS cum slice) -> merge
// R9:  16M random gathers pinned at L2 request wall -> 512 bins x 8K nodes;
//      gather reads a 32KB LDS slice; global traffic streams.
// R10: rank determinism not needed for output determinism -> LDS atomicAdd.
// R12/R13: match segment-copy group width to mean run length (CHUNK/NB).
// R16: XCD-contiguous chunk swizzle (scatter/merge) restores L2 line merging.
// R17/R18: ILP walk loads must be unconditional BUT retired chains must park
//      at j=0 (L1 broadcast line) — random retired loads cost +134MB FETCH.
// R19: walk3 still request-concurrency-limited (3.6TB/s, VALU 4%, occ 62%)
//      -> ILP-8 chains/thread; merge copy-in ILP-2 -> ILP-4.

typedef float v2f __attribute__((ext_vector_type(2)));
typedef float v4f __attribute__((ext_vector_type(4)));
typedef int   v4i __attribute__((ext_vector_type(4)));

#define NB 512          // bins; bin width 1<<shift <= 8192 nodes (32KB slice)
#define CHUNK_PX 4096   // pixels per chunk block
#define CV4 1024        // v4i quads per chunk

// ---------------- A: fused gate+pack | per-chunk histogram (LDS atomics) ------
__global__ __launch_bounds__(256) void k_gate_count512(
        const float* __restrict__ attrs, const float* __restrict__ w,
        const float* __restrict__ bias, const float* __restrict__ residue,
        const int* __restrict__ parent, int2* __restrict__ packed, int N,
        const int* __restrict__ ptn, unsigned short* __restrict__ wcnt,
        int shift, int g1) {
    __shared__ int hist[NB];
    if ((int)blockIdx.x >= g1) {
        int chunk = blockIdx.x - g1;
        int tid = threadIdx.x;
        for (int i = tid; i < NB; i += 256) hist[i] = 0;
        __syncthreads();
        const v4i* p4 = reinterpret_cast<const v4i*>(ptn) + (size_t)chunk * CV4;
        for (int t = 0; t < CV4/256; ++t) {
            v4i ia = __builtin_nontemporal_load(p4 + t*256 + tid);
            atomicAdd(&hist[ia.x >> shift], 1);
            atomicAdd(&hist[ia.y >> shift], 1);
            atomicAdd(&hist[ia.z >> shift], 1);
            atomicAdd(&hist[ia.w >> shift], 1);
        }
        __syncthreads();
        unsigned short* wc = wcnt + (size_t)chunk * NB;
        for (int i = tid; i < NB; i += 256) wc[i] = (unsigned short)hist[i];
        return;
    }
    int i = blockIdx.x * blockDim.x + threadIdx.x;
    if (i > N) return;
    if (i == N) { int2 p; p.x = N; p.y = __float_as_int(0.0f); packed[N] = p; return; }
    const v2f* a2 = reinterpret_cast<const v2f*>(attrs + (size_t)i * 6);
    v2f a0  = __builtin_nontemporal_load(a2 + 0);
    v2f a1  = __builtin_nontemporal_load(a2 + 1);
    v2f a2v = __builtin_nontemporal_load(a2 + 2);
    float logit = bias[0]
                + a0.x  * w[0] + a0.y  * w[1]
                + a1.x  * w[2] + a1.y  * w[3]
                + a2v.x * w[4] + a2v.y * w[5];
    float s = fminf(fmaxf(100.0f * logit, -12.0f), 12.0f);
    float gate = 1.0f / (1.0f + __expf(-s));
    float vv = gate * __builtin_nontemporal_load(residue + i);
    int2 p; p.x = __builtin_nontemporal_load(parent + i); p.y = __float_as_int(vv);
    packed[i] = p;
}

// ---------------- scan stage 1: group partials (32 chunks per group) ----------
__global__ __launch_bounds__(512) void k_scanA(const unsigned short* __restrict__ wcnt,
                                               int* __restrict__ P) {
    int g = blockIdx.x, b = threadIdx.x;
    const unsigned short* base = wcnt + (size_t)g * 32 * NB;
    int s = 0;
    for (int i = 0; i < 32; ++i) s += base[(size_t)i*NB + b];
    P[(size_t)g*NB + b] = s;
}

// ---------------- scan stage 2: bin totals + 64-aligned bin starts ------------
__global__ __launch_bounds__(512) void k_scanB(int* __restrict__ P,
                                               int* __restrict__ binStart,
                                               int* __restrict__ binCnt, int nGroups) {
    int b = threadIdx.x, lane = b & 63, wave = b >> 6;
    int tot = 0;
    for (int g = 0; g < nGroups; ++g) {
        int t = P[(size_t)g*NB + b]; P[(size_t)g*NB + b] = tot; tot += t;  // excl in place
    }
    binCnt[b] = tot;
    int pad = (tot + 63) & ~63;
    int inc = pad;
    #pragma unroll
    for (int d = 1; d < 64; d <<= 1) { int o = __shfl_up(inc, d); if (lane >= d) inc += o; }
    __shared__ int wsum[8];
    if (lane == 63) wsum[wave] = inc;
    __syncthreads();
    int wb = 0;
    for (int ww = 0; ww < wave; ++ww) wb += wsum[ww];
    binStart[b] = wb + inc - pad;
}

// ---------------- scan stage 3: per-chunk bases -------------------------------
__global__ __launch_bounds__(512) void k_scanC(const unsigned short* __restrict__ wcnt,
                                               const int* __restrict__ P,
                                               const int* __restrict__ binStart,
                                               int* __restrict__ bases) {
    int g = blockIdx.x, b = threadIdx.x;
    int run = binStart[b] + P[(size_t)g*NB + b];
    for (int i = 0; i < 32; ++i) {
        size_t c = (size_t)g*32 + i;
        bases[c*NB + b] = run;
        run += wcnt[c*NB + b];
    }
}

// ---------------- walks -------------------------------------------------------
__global__ void k_walk_lvl0(const int2* __restrict__ packed,
                            float* __restrict__ cum, int hi, int N) {
    int i = blockIdx.x * blockDim.x + threadIdx.x;
    if (i >= hi) return;
    float s = 0.0f; int j = i;
    while (j != N) { int2 pv = packed[j]; s += __int_as_float(pv.y); j = pv.x; }
    cum[i] = s;
}

// ILP-8 chained walk: 8 loads always in flight; retired chains PARK at j=0
// (packed[0] = one broadcast line, L1-free). Final ancestor kept in f*.
#define WSTEP(K) if (a##K) { s##K += __int_as_float(p##K.y); int nj = p##K.x; \
    if (nj >= cutoff) j##K = nj; else { f##K = nj; j##K = 0; a##K = false; } }
__global__ void k_walk_lvl8(const int2* __restrict__ packed,
                            float* __restrict__ cum, int lo, int hi, int cutoff) {
    int T = gridDim.x * blockDim.x;
    int i0 = lo + blockIdx.x * blockDim.x + threadIdx.x;
    int i1 = i0 +   T, i2 = i0 + 2*T, i3 = i0 + 3*T;
    int i4 = i0 + 4*T, i5 = i0 + 5*T, i6 = i0 + 6*T, i7 = i0 + 7*T;
    bool a0 = i0 < hi, a1 = i1 < hi, a2 = i2 < hi, a3 = i3 < hi;
    bool a4 = i4 < hi, a5 = i5 < hi, a6 = i6 < hi, a7 = i7 < hi;
    int j0 = a0 ? i0 : 0, j1 = a1 ? i1 : 0, j2 = a2 ? i2 : 0, j3 = a3 ? i3 : 0;
    int j4 = a4 ? i4 : 0, j5 = a5 ? i5 : 0, j6 = a6 ? i6 : 0, j7 = a7 ? i7 : 0;
    int f0 = 0, f1 = 0, f2 = 0, f3 = 0, f4 = 0, f5 = 0, f6 = 0, f7 = 0;
    float s0 = 0, s1 = 0, s2 = 0, s3 = 0, s4 = 0, s5 = 0, s6 = 0, s7 = 0;
    while (a0 | a1 | a2 | a3 | a4 | a5 | a6 | a7) {
        int2 p0 = packed[j0];         // 8 independent loads in flight
        int2 p1 = packed[j1];
        int2 p2 = packed[j2];
        int2 p3 = packed[j3];
        int2 p4 = packed[j4];
        int2 p5 = packed[j5];
        int2 p6 = packed[j6];
        int2 p7 = packed[j7];
        WSTEP(0) WSTEP(1) WSTEP(2) WSTEP(3)
        WSTEP(4) WSTEP(5) WSTEP(6) WSTEP(7)
    }
    if (i0 < hi) cum[i0] = s0 + cum[f0];
    if (i1 < hi) cum[i1] = s1 + cum[f1];
    if (i2 < hi) cum[i2] = s2 + cum[f2];
    if (i3 < hi) cum[i3] = s3 + cum[f3];
    if (i4 < hi) cum[i4] = s4 + cum[f4];
    if (i5 < hi) cum[i5] = s5 + cum[f5];
    if (i6 < hi) cum[i6] = s6 + cum[f6];
    if (i7 < hi) cum[i7] = s7 + cum[f7];
}
#undef WSTEP

// XCD-contiguous chunk swizzle: XCD k owns chunks [k*q, (k+1)*q) so adjacent
// 32B run segments merge in the same L2.
__device__ __forceinline__ int swz_chunk(int bid, int q) {
    return q ? (bid & 7) * q + (bid >> 3) : bid;
}

// ---------------- scatter: 512 thr, LDS-atomic ranks, 8-lane run write-out ----
__global__ __launch_bounds__(512) void k_scatter512(
        const int* __restrict__ ptn, const unsigned short* __restrict__ wcnt,
        const int* __restrict__ bases, int* __restrict__ nv,
        unsigned short* __restrict__ slotLocal, int shift, int q8) {
    __shared__ int cnt[NB];
    __shared__ int alloc[NB];          // exscan start, advanced by atomics
    __shared__ int sbase[NB];
    __shared__ int ldss[CHUNK_PX];
    __shared__ int wsum[8];
    int chunk = swz_chunk(blockIdx.x, q8);
    int tid = threadIdx.x, lane = tid & 63, wave = tid >> 6;
    const unsigned short* wc = wcnt + (size_t)chunk * NB;
    const int* bs = bases + (size_t)chunk * NB;
    if (tid < NB) { cnt[tid] = wc[tid]; sbase[tid] = bs[tid]; }
    __syncthreads();
    // exclusive scan, 1 bin per thread (512 threads = 8 waves)
    {
        int s = (tid < NB) ? cnt[tid] : 0;
        int inc = s;
        #pragma unroll
        for (int d = 1; d < 64; d <<= 1) { int o = __shfl_up(inc, d); if (lane >= d) inc += o; }
        if (lane == 63) wsum[wave] = inc;
        __syncthreads();
        int wb = 0;
        for (int ww = 0; ww < wave; ++ww) wb += wsum[ww];
        if (tid < NB) alloc[tid] = wb + inc - s;
    }
    __syncthreads();
    const v4i* p4 = reinterpret_cast<const v4i*>(ptn) + (size_t)chunk * CV4;
    unsigned long long* sl8 = reinterpret_cast<unsigned long long*>(slotLocal)
                              + (size_t)chunk * CV4;
    #pragma unroll
    for (int t = 0; t < CV4/512; ++t) {
        v4i ia = __builtin_nontemporal_load(p4 + t*512 + tid);
        int s0 = atomicAdd(&alloc[ia.x >> shift], 1);
        int s1 = atomicAdd(&alloc[ia.y >> shift], 1);
        int s2 = atomicAdd(&alloc[ia.z >> shift], 1);
        int s3 = atomicAdd(&alloc[ia.w >> shift], 1);
        ldss[s0] = ia.x; ldss[s1] = ia.y; ldss[s2] = ia.z; ldss[s3] = ia.w;
        unsigned long long pk = (unsigned long long)(unsigned)s0
                              | ((unsigned long long)(unsigned)s1 << 16)
                              | ((unsigned long long)(unsigned)s2 << 32)
                              | ((unsigned long long)(unsigned)s3 << 48);
        sl8[t*512 + tid] = pk;
    }
    __syncthreads();
    // 8-lane-group per bin write-out; run start = alloc[b] - cnt[b]
    int grp = tid >> 3;          // 64 groups of 8 lanes
    int l8 = tid & 7;
    for (int b = grp; b < NB; b += 64) {
        int n = cnt[b];
        int st = alloc[b] - n;
        int dst = sbase[b];
        for (int i = l8; i < n; i += 8)
            nv[dst + i] = ldss[st + i];
    }
}

// ---------------- gather: LDS-staged 32KB cum slice, in-place int->float ------
__global__ __launch_bounds__(512) void k_gather512(
        int* __restrict__ nv, const float* __restrict__ cum,
        const int* __restrict__ binStart, const int* __restrict__ binCnt,
        int shift, int N) {
    __shared__ float slice[8192];
    int b = blockIdx.x;
    int base = b << shift;
    int W = 1 << shift;
    for (int i = threadIdx.x; i < W; i += 512) {
        int idx = base + i;
        slice[i] = (idx < N) ? cum[idx] : 0.0f;
    }
    __syncthreads();
    int s = binStart[b], cnt = binCnt[b];
    int nq = cnt >> 2;
    v4i* np = reinterpret_cast<v4i*>(nv + s);      // 64-aligned starts
    v4f* vp = reinterpret_cast<v4f*>(nv + s);
    for (int q = threadIdx.x; q < nq; q += 512) {
        v4i na = __builtin_nontemporal_load(np + q);
        v4f va;
        va.x = slice[na.x - base];
        va.y = slice[na.y - base];
        va.z = slice[na.z - base];
        va.w = slice[na.w - base];
        vp[q] = va;                                 // in-place: same thread, same slot
    }
    int r = cnt & 3;
    if ((int)threadIdx.x < r) {
        int i = s + nq*4 + threadIdx.x;
        float v = slice[nv[i] - base];
        reinterpret_cast<float*>(nv)[i] = v;
    }
}

// ---------------- merge: 512 thr, ILP-4 quad-bin copy-in, LDS resolve ---------
__global__ __launch_bounds__(512) void k_merge512(
        const unsigned short* __restrict__ wcnt, const int* __restrict__ bases,
        const float* __restrict__ nvf, const unsigned short* __restrict__ slotLocal,
        float* __restrict__ out, int q8) {
    __shared__ int cnt[NB];
    __shared__ int chEx[NB];
    __shared__ int sbase[NB];
    __shared__ float ldsv[CHUNK_PX];
    __shared__ int wsum[8];
    int chunk = swz_chunk(blockIdx.x, q8);
    int tid = threadIdx.x, lane = tid & 63, wave = tid >> 6;
    const unsigned short* wc = wcnt + (size_t)chunk * NB;
    const int* bs = bases + (size_t)chunk * NB;
    if (tid < NB) { cnt[tid] = wc[tid]; sbase[tid] = bs[tid]; }
    __syncthreads();
    // exclusive scan, 1 bin per thread (512 threads = 8 waves)
    {
        int s = (tid < NB) ? cnt[tid] : 0;
        int inc = s;
        #pragma unroll
        for (int d = 1; d < 64; d <<= 1) { int o = __shfl_up(inc, d); if (lane >= d) inc += o; }
        if (lane == 63) wsum[wave] = inc;
        __syncthreads();
        int wb = 0;
        for (int ww = 0; ww < wave; ++ww) wb += wsum[ww];
        if (tid < NB) chEx[tid] = wb + inc - s;
    }
    __syncthreads();
    // ILP-4 quad-bin copy-in: 64 groups of 8 lanes; bins (b,b+128,b+256,b+384)
    // give four independent global loads in flight per iteration.
    {
        int grp = tid >> 3;          // 64 groups
        int l8 = tid & 7;
        #pragma unroll
        for (int t = 0; t < 2; ++t) {
            int b1 = grp + 64*t;     // < 128
            int b2 = b1 + 128, b3 = b1 + 256, b4 = b1 + 384;
            int n1 = cnt[b1], st1 = chEx[b1], src1 = sbase[b1];
            int n2 = cnt[b2], st2 = chEx[b2], src2 = sbase[b2];
            int n3 = cnt[b3], st3 = chEx[b3], src3 = sbase[b3];
            int n4 = cnt[b4], st4 = chEx[b4], src4 = sbase[b4];
            int nm = n1 > n2 ? n1 : n2;
            nm = nm > n3 ? nm : n3;
            nm = nm > n4 ? nm : n4;
            for (int i = l8; i < nm; i += 8) {
                float v1 = 0.0f, v2 = 0.0f, v3 = 0.0f, v4 = 0.0f;
                bool q1 = i < n1, q2 = i < n2, q3 = i < n3, q4 = i < n4;
                if (q1) v1 = nvf[src1 + i];
                if (q2) v2 = nvf[src2 + i];
                if (q3) v3 = nvf[src3 + i];
                if (q4) v4 = nvf[src4 + i];
                if (q1) ldsv[st1 + i] = v1;
                if (q2) ldsv[st2 + i] = v2;
                if (q3) ldsv[st3 + i] = v3;
                if (q4) ldsv[st4 + i] = v4;
            }
        }
    }
    __syncthreads();
    const unsigned long long* sl8 = reinterpret_cast<const unsigned long long*>(slotLocal)
                                    + (size_t)chunk * CV4;
    v4f* o4 = reinterpret_cast<v4f*>(out) + (size_t)chunk * CV4;
    #pragma unroll
    for (int t = 0; t < CV4/512; ++t) {
        unsigned long long pk = __builtin_nontemporal_load(sl8 + t*512 + tid);
        v4f o;
        o.x = ldsv[pk & 0xFFFF];
        o.y = ldsv[(pk >> 16) & 0xFFFF];
        o.z = ldsv[(pk >> 32) & 0xFFFF];
        o.w = ldsv[(pk >> 48) & 0xFFFF];
        o4[t*512 + tid] = o;                 // coalesced pixel-order write
    }
}

// ---------------- fallback: direct pixel gather -------------------------------
__global__ void k_pixel_gather(const float* __restrict__ cum,
                               const int* __restrict__ ptn,
                               float* __restrict__ out, int M) {
    int t = blockIdx.x * blockDim.x + threadIdx.x;
    int base = t * 4;
    if (base + 3 < M) {
        v4i idx = __builtin_nontemporal_load(reinterpret_cast<const v4i*>(ptn) + t);
        float4 o;
        o.x = cum[idx.x]; o.y = cum[idx.y]; o.z = cum[idx.z]; o.w = cum[idx.w];
        reinterpret_cast<float4*>(out)[t] = o;
    } else {
        for (int p = base; p < M; ++p) out[p] = cum[ptn[p]];
    }
}

extern "C" void kernel_launch(void* const* d_in, const int* in_sizes, int n_in,
                              void* d_out, int out_size, void* d_ws, size_t ws_size,
                              hipStream_t stream) {
    const float* attrs   = (const float*)d_in[0];
    const float* weight  = (const float*)d_in[1];
    const float* bias    = (const float*)d_in[2];
    const float* residue = (const float*)d_in[3];
    const int*   parent  = (const int*)d_in[4];
    const int*   ptn     = (const int*)d_in[5];
    float* out = (float*)d_out;

    const int N  = in_sizes[3];
    const int HW = in_sizes[5];
    const int BLK = 256;

    int shift = 0;
    while (((long)(N - 1) >> shift) >= NB) ++shift;
    int nBins = (int)(((long)(N - 1) >> shift) + 1);

    const int nChunks = HW / CHUNK_PX;
    const int nGroups = nChunks / 32;
    const int q8 = (nChunks % 8 == 0) ? nChunks / 8 : 0;

    auto align256 = [](size_t x) { return (x + 255) & ~(size_t)255; };
    const size_t cumB   = align256((size_t)(N + 1) * 4);
    const size_t pkB    = (size_t)(N + 1) * 8;
    const size_t slB    = (size_t)HW * 2;
    const size_t regA   = align256(pkB > slB ? pkB : slB);   // packed / slotLocal alias
    const size_t nvB    = align256(((size_t)HW + (size_t)NB*64) * 4);
    const size_t wcntB  = align256((size_t)nChunks * NB * 2);
    const size_t PB     = align256((size_t)nGroups * NB * 4);
    const size_t basesB = align256((size_t)nChunks * NB * 4);
    const size_t need   = cumB + regA + nvB + wcntB + PB + basesB + 4096;

    float* cum    = (float*)d_ws;
    int2*  packed = (int2*)((char*)d_ws + cumB);
    unsigned short* slotLocal = (unsigned short*)((char*)d_ws + cumB);  // alias (packed dead)
    int*   nv     = (int*)((char*)d_ws + cumB + regA);
    unsigned short* wcnt = (unsigned short*)((char*)d_ws + cumB + regA + nvB);
    int*   P      = (int*)((char*)d_ws + cumB + regA + nvB + wcntB);
    int*   bases  = (int*)((char*)d_ws + cumB + regA + nvB + wcntB + PB);
    int*   binStart = (int*)((char*)d_ws + cumB + regA + nvB + wcntB + PB + basesB);
    int*   binCnt   = binStart + NB;

    bool binnedOK = (HW % CHUNK_PX == 0) && (nChunks % 32 == 0) && (nChunks >= 32) &&
                    (shift <= 13) && (ws_size >= need) && (N >= 2);

    // A) gate+pack | count
    int g1 = (N + 1 + BLK - 1) / BLK;
    int gC = binnedOK ? nChunks : 0;
    k_gate_count512<<<g1 + gC, BLK, 0, stream>>>(attrs, weight, bias, residue,
                                                 parent, packed, N,
                                                 ptn, wcnt, shift, g1);

    if (binnedOK) {
        k_scanA<<<nGroups, 512, 0, stream>>>(wcnt, P);
        k_scanB<<<1, 512, 0, stream>>>(P, binStart, binCnt, nGroups);
        k_scanC<<<nGroups, 512, 0, stream>>>(wcnt, P, binStart, bases);
    }

    // walks: cutoffs 16K / 256K / 1M / N
    int c0 = 16384;   if (c0 > N) c0 = N;
    int c1 = 262144;  if (c1 > N) c1 = N;
    int c2 = 1048576; if (c2 > N) c2 = N;

    k_walk_lvl0<<<(c0 + BLK - 1) / BLK, BLK, 0, stream>>>(packed, cum, c0, N);
    if (c1 > c0) {
        int n1 = c1 - c0;
        k_walk_lvl8<<<(n1 + 8*BLK - 1) / (8*BLK), BLK, 0, stream>>>(packed, cum, c0, c1, c0);
    }
    if (c2 > c1) {
        int n2 = c2 - c1;
        k_walk_lvl8<<<(n2 + 8*BLK - 1) / (8*BLK), BLK, 0, stream>>>(packed, cum, c1, c2, c1);
    }
    if (N > c2) {
        int n3 = N - c2;
        k_walk_lvl8<<<(n3 + 8*BLK - 1) / (8*BLK), BLK, 0, stream>>>(packed, cum, c2, N, c2);
    }

    if (binnedOK) {
        // packed is dead from here on; slotLocal reuses its region
        k_scatter512<<<nChunks, 512, 0, stream>>>(ptn, wcnt, bases, nv, slotLocal,
                                                  shift, q8);
        k_gather512<<<nBins, 512, 0, stream>>>(nv, cum, binStart, binCnt, shift, N);
        k_merge512<<<nChunks, 512, 0, stream>>>(wcnt, bases, (const float*)nv,
                                                slotLocal, out, q8);
    } else {
        int nQuads = (HW + 3) / 4;
        k_pixel_gather<<<(nQuads + BLK - 1) / BLK, BLK, 0, stream>>>(cum, ptn, out, HW);
    }
}

// Round 20
// 267.028 us; speedup vs baseline: 1.1079x; 1.1079x over previous
//
#include <hip/hip_runtime.h>
#include <hip/hip_bf16.h>

// Connected filter:
//   vals[i] = sigmoid(clamp(100*(attrs[i]·w + b), ±12)) * residue[i]
//   cum[i]  = sum of vals along parent chain from i (dummy N terminates)
//   out[p]  = cum[pixel_to_node[p]]
// parent[i] < i (topological), parent[N] = N (dummy, val 0).
//
// Pipeline (serial — R8/R9/R14: NO fusion of saturating phases pays):
//   gate+pack | count -> scanA/B/C -> walks L0/L1/L2/L3 -> scatter -> gather
//   (LDS cum slice) -> merge
// R9:  16M random gathers pinned at L2 request wall -> 512 bins x 8K nodes;
//      gather reads a 32KB LDS slice; global traffic streams.
// R10: rank determinism not needed for output determinism -> LDS atomicAdd.
// R12/R13: match segment-copy group width to mean run length (CHUNK/NB).
// R16: XCD-contiguous chunk swizzle (scatter/merge) restores L2 line merging.
// R17/R18: ILP walk loads unconditional BUT retired chains park at j=0.
// R19: walk ILP-8 null (request wall, not concurrency) -> back to ILP-4;
//      merge ILP-4 copy-in regressed -> back to ILP-2.
// R20: CHUNK 4096->8192 with 1024-thr scatter/merge blocks: 38KB LDS x 2
//      blk/CU = 32 waves (100% occ, was 45-52%) AND 64B run segments
//      (halves scattered-request count). 16-lane copy groups (run=16).

typedef float v2f __attribute__((ext_vector_type(2)));
typedef float v4f __attribute__((ext_vector_type(4)));
typedef int   v4i __attribute__((ext_vector_type(4)));

#define NB 512          // bins; bin width 1<<shift <= 8192 nodes (32KB slice)
#define CHUNK_PX 8192   // pixels per chunk block
#define CV4 2048        // v4i quads per chunk

// ---------------- A: fused gate+pack | per-chunk histogram (LDS atomics) ------
__global__ __launch_bounds__(256) void k_gate_count512(
        const float* __restrict__ attrs, const float* __restrict__ w,
        const float* __restrict__ bias, const float* __restrict__ residue,
        const int* __restrict__ parent, int2* __restrict__ packed, int N,
        const int* __restrict__ ptn, unsigned short* __restrict__ wcnt,
        int shift, int g1) {
    __shared__ int hist[NB];
    if ((int)blockIdx.x >= g1) {
        int chunk = blockIdx.x - g1;
        int tid = threadIdx.x;
        for (int i = tid; i < NB; i += 256) hist[i] = 0;
        __syncthreads();
        const v4i* p4 = reinterpret_cast<const v4i*>(ptn) + (size_t)chunk * CV4;
        for (int t = 0; t < CV4/256; ++t) {
            v4i ia = __builtin_nontemporal_load(p4 + t*256 + tid);
            atomicAdd(&hist[ia.x >> shift], 1);
            atomicAdd(&hist[ia.y >> shift], 1);
            atomicAdd(&hist[ia.z >> shift], 1);
            atomicAdd(&hist[ia.w >> shift], 1);
        }
        __syncthreads();
        unsigned short* wc = wcnt + (size_t)chunk * NB;
        for (int i = tid; i < NB; i += 256) wc[i] = (unsigned short)hist[i];
        return;
    }
    int i = blockIdx.x * blockDim.x + threadIdx.x;
    if (i > N) return;
    if (i == N) { int2 p; p.x = N; p.y = __float_as_int(0.0f); packed[N] = p; return; }
    const v2f* a2 = reinterpret_cast<const v2f*>(attrs + (size_t)i * 6);
    v2f a0  = __builtin_nontemporal_load(a2 + 0);
    v2f a1  = __builtin_nontemporal_load(a2 + 1);
    v2f a2v = __builtin_nontemporal_load(a2 + 2);
    float logit = bias[0]
                + a0.x  * w[0] + a0.y  * w[1]
                + a1.x  * w[2] + a1.y  * w[3]
                + a2v.x * w[4] + a2v.y * w[5];
    float s = fminf(fmaxf(100.0f * logit, -12.0f), 12.0f);
    float gate = 1.0f / (1.0f + __expf(-s));
    float vv = gate * __builtin_nontemporal_load(residue + i);
    int2 p; p.x = __builtin_nontemporal_load(parent + i); p.y = __float_as_int(vv);
    packed[i] = p;
}

// ---------------- scan stage 1: group partials (32 chunks per group) ----------
__global__ __launch_bounds__(512) void k_scanA(const unsigned short* __restrict__ wcnt,
                                               int* __restrict__ P) {
    int g = blockIdx.x, b = threadIdx.x;
    const unsigned short* base = wcnt + (size_t)g * 32 * NB;
    int s = 0;
    for (int i = 0; i < 32; ++i) s += base[(size_t)i*NB + b];
    P[(size_t)g*NB + b] = s;
}

// ---------------- scan stage 2: bin totals + 64-aligned bin starts ------------
__global__ __launch_bounds__(512) void k_scanB(int* __restrict__ P,
                                               int* __restrict__ binStart,
                                               int* __restrict__ binCnt, int nGroups) {
    int b = threadIdx.x, lane = b & 63, wave = b >> 6;
    int tot = 0;
    for (int g = 0; g < nGroups; ++g) {
        int t = P[(size_t)g*NB + b]; P[(size_t)g*NB + b] = tot; tot += t;  // excl in place
    }
    binCnt[b] = tot;
    int pad = (tot + 63) & ~63;
    int inc = pad;
    #pragma unroll
    for (int d = 1; d < 64; d <<= 1) { int o = __shfl_up(inc, d); if (lane >= d) inc += o; }
    __shared__ int wsum[8];
    if (lane == 63) wsum[wave] = inc;
    __syncthreads();
    int wb = 0;
    for (int ww = 0; ww < wave; ++ww) wb += wsum[ww];
    binStart[b] = wb + inc - pad;
}

// ---------------- scan stage 3: per-chunk bases -------------------------------
__global__ __launch_bounds__(512) void k_scanC(const unsigned short* __restrict__ wcnt,
                                               const int* __restrict__ P,
                                               const int* __restrict__ binStart,
                                               int* __restrict__ bases) {
    int g = blockIdx.x, b = threadIdx.x;
    int run = binStart[b] + P[(size_t)g*NB + b];
    for (int i = 0; i < 32; ++i) {
        size_t c = (size_t)g*32 + i;
        bases[c*NB + b] = run;
        run += wcnt[c*NB + b];
    }
}

// ---------------- walks -------------------------------------------------------
__global__ void k_walk_lvl0(const int2* __restrict__ packed,
                            float* __restrict__ cum, int hi, int N) {
    int i = blockIdx.x * blockDim.x + threadIdx.x;
    if (i >= hi) return;
    float s = 0.0f; int j = i;
    while (j != N) { int2 pv = packed[j]; s += __int_as_float(pv.y); j = pv.x; }
    cum[i] = s;
}

// ILP-4 chained walk (R18 best): 4 loads always in flight; retired chains PARK
// at j=0 (packed[0] = broadcast line, L1-free). Final ancestor kept in f*.
__global__ void k_walk_lvl4(const int2* __restrict__ packed,
                            float* __restrict__ cum, int lo, int hi, int cutoff) {
    int T = gridDim.x * blockDim.x;
    int i0 = lo + blockIdx.x * blockDim.x + threadIdx.x;
    int i1 = i0 + T, i2 = i0 + 2*T, i3 = i0 + 3*T;
    bool a0 = i0 < hi, a1 = i1 < hi, a2 = i2 < hi, a3 = i3 < hi;
    int j0 = a0 ? i0 : 0, j1 = a1 ? i1 : 0, j2 = a2 ? i2 : 0, j3 = a3 ? i3 : 0;
    int f0 = 0, f1 = 0, f2 = 0, f3 = 0;
    float s0 = 0, s1 = 0, s2 = 0, s3 = 0;
    while (a0 | a1 | a2 | a3) {
        int2 p0 = packed[j0];         // always issued; parked chains hit L1
        int2 p1 = packed[j1];
        int2 p2 = packed[j2];
        int2 p3 = packed[j3];
        if (a0) { s0 += __int_as_float(p0.y); int nj = p0.x;
                  if (nj >= cutoff) j0 = nj; else { f0 = nj; j0 = 0; a0 = false; } }
        if (a1) { s1 += __int_as_float(p1.y); int nj = p1.x;
                  if (nj >= cutoff) j1 = nj; else { f1 = nj; j1 = 0; a1 = false; } }
        if (a2) { s2 += __int_as_float(p2.y); int nj = p2.x;
                  if (nj >= cutoff) j2 = nj; else { f2 = nj; j2 = 0; a2 = false; } }
        if (a3) { s3 += __int_as_float(p3.y); int nj = p3.x;
                  if (nj >= cutoff) j3 = nj; else { f3 = nj; j3 = 0; a3 = false; } }
    }
    if (i0 < hi) cum[i0] = s0 + cum[f0];
    if (i1 < hi) cum[i1] = s1 + cum[f1];
    if (i2 < hi) cum[i2] = s2 + cum[f2];
    if (i3 < hi) cum[i3] = s3 + cum[f3];
}

// XCD-contiguous chunk swizzle: XCD k owns chunks [k*q, (k+1)*q) so adjacent
// run segments merge in the same L2.
__device__ __forceinline__ int swz_chunk(int bid, int q) {
    return q ? (bid & 7) * q + (bid >> 3) : bid;
}

// ---------------- scatter: 1024 thr, LDS-atomic ranks, 16-lane run write-out --
__global__ __launch_bounds__(1024) void k_scatter512(
        const int* __restrict__ ptn, const unsigned short* __restrict__ wcnt,
        const int* __restrict__ bases, int* __restrict__ nv,
        unsigned short* __restrict__ slotLocal, int shift, int q8) {
    __shared__ int cnt[NB];
    __shared__ int alloc[NB];          // exscan start, advanced by atomics
    __shared__ int sbase[NB];
    __shared__ int ldss[CHUNK_PX];
    __shared__ int wsum[16];
    int chunk = swz_chunk(blockIdx.x, q8);
    int tid = threadIdx.x, lane = tid & 63, wave = tid >> 6;
    const unsigned short* wc = wcnt + (size_t)chunk * NB;
    const int* bs = bases + (size_t)chunk * NB;
    if (tid < NB) { cnt[tid] = wc[tid]; sbase[tid] = bs[tid]; }
    __syncthreads();
    // exclusive scan, 1 bin per thread (bins in waves 0-7 of 16)
    {
        int s = (tid < NB) ? cnt[tid] : 0;
        int inc = s;
        #pragma unroll
        for (int d = 1; d < 64; d <<= 1) { int o = __shfl_up(inc, d); if (lane >= d) inc += o; }
        if (lane == 63) wsum[wave] = inc;
        __syncthreads();
        int wb = 0;
        for (int ww = 0; ww < wave; ++ww) wb += wsum[ww];
        if (tid < NB) alloc[tid] = wb + inc - s;
    }
    __syncthreads();
    const v4i* p4 = reinterpret_cast<const v4i*>(ptn) + (size_t)chunk * CV4;
    unsigned long long* sl8 = reinterpret_cast<unsigned long long*>(slotLocal)
                              + (size_t)chunk * CV4;
    #pragma unroll
    for (int t = 0; t < CV4/1024; ++t) {
        v4i ia = __builtin_nontemporal_load(p4 + t*1024 + tid);
        int s0 = atomicAdd(&alloc[ia.x >> shift], 1);
        int s1 = atomicAdd(&alloc[ia.y >> shift], 1);
        int s2 = atomicAdd(&alloc[ia.z >> shift], 1);
        int s3 = atomicAdd(&alloc[ia.w >> shift], 1);
        ldss[s0] = ia.x; ldss[s1] = ia.y; ldss[s2] = ia.z; ldss[s3] = ia.w;
        unsigned long long pk = (unsigned long long)(unsigned)s0
                              | ((unsigned long long)(unsigned)s1 << 16)
                              | ((unsigned long long)(unsigned)s2 << 32)
                              | ((unsigned long long)(unsigned)s3 << 48);
        sl8[t*1024 + tid] = pk;
    }
    __syncthreads();
    // 16-lane-group per bin write-out (mean run = CHUNK/NB = 16);
    // run start = alloc[b] - cnt[b] (final alloc = start + count)
    int grp = tid >> 4;          // 64 groups of 16 lanes
    int l16 = tid & 15;
    for (int b = grp; b < NB; b += 64) {
        int n = cnt[b];
        int st = alloc[b] - n;
        int dst = sbase[b];
        for (int i = l16; i < n; i += 16)
            nv[dst + i] = ldss[st + i];
    }
}

// ---------------- gather: LDS-staged 32KB cum slice, in-place int->float ------
__global__ __launch_bounds__(512) void k_gather512(
        int* __restrict__ nv, const float* __restrict__ cum,
        const int* __restrict__ binStart, const int* __restrict__ binCnt,
        int shift, int N) {
    __shared__ float slice[8192];
    int b = blockIdx.x;
    int base = b << shift;
    int W = 1 << shift;
    for (int i = threadIdx.x; i < W; i += 512) {
        int idx = base + i;
        slice[i] = (idx < N) ? cum[idx] : 0.0f;
    }
    __syncthreads();
    int s = binStart[b], cnt = binCnt[b];
    int nq = cnt >> 2;
    v4i* np = reinterpret_cast<v4i*>(nv + s);      // 64-aligned starts
    v4f* vp = reinterpret_cast<v4f*>(nv + s);
    for (int q = threadIdx.x; q < nq; q += 512) {
        v4i na = __builtin_nontemporal_load(np + q);
        v4f va;
        va.x = slice[na.x - base];
        va.y = slice[na.y - base];
        va.z = slice[na.z - base];
        va.w = slice[na.w - base];
        vp[q] = va;                                 // in-place: same thread, same slot
    }
    int r = cnt & 3;
    if ((int)threadIdx.x < r) {
        int i = s + nq*4 + threadIdx.x;
        float v = slice[nv[i] - base];
        reinterpret_cast<float*>(nv)[i] = v;
    }
}

// ---------------- merge: 1024 thr, ILP-2 paired-bin copy-in, LDS resolve ------
__global__ __launch_bounds__(1024) void k_merge512(
        const unsigned short* __restrict__ wcnt, const int* __restrict__ bases,
        const float* __restrict__ nvf, const unsigned short* __restrict__ slotLocal,
        float* __restrict__ out, int q8) {
    __shared__ int cnt[NB];
    __shared__ int chEx[NB];
    __shared__ int sbase[NB];
    __shared__ float ldsv[CHUNK_PX];
    __shared__ int wsum[16];
    int chunk = swz_chunk(blockIdx.x, q8);
    int tid = threadIdx.x, lane = tid & 63, wave = tid >> 6;
    const unsigned short* wc = wcnt + (size_t)chunk * NB;
    const int* bs = bases + (size_t)chunk * NB;
    if (tid < NB) { cnt[tid] = wc[tid]; sbase[tid] = bs[tid]; }
    __syncthreads();
    // exclusive scan, 1 bin per thread
    {
        int s = (tid < NB) ? cnt[tid] : 0;
        int inc = s;
        #pragma unroll
        for (int d = 1; d < 64; d <<= 1) { int o = __shfl_up(inc, d); if (lane >= d) inc += o; }
        if (lane == 63) wsum[wave] = inc;
        __syncthreads();
        int wb = 0;
        for (int ww = 0; ww < wave; ++ww) wb += wsum[ww];
        if (tid < NB) chEx[tid] = wb + inc - s;
    }
    __syncthreads();
    // ILP-2 paired-bin copy-in: 64 groups of 16 lanes; pair (b, b+256) so two
    // independent global loads are in flight per iteration.
    {
        int grp = tid >> 4;          // 64 groups
        int l16 = tid & 15;
        #pragma unroll
        for (int t = 0; t < 4; ++t) {
            int b1 = grp + 64*t;     // < 256
            int b2 = b1 + 256;
            int n1 = cnt[b1], st1 = chEx[b1], src1 = sbase[b1];
            int n2 = cnt[b2], st2 = chEx[b2], src2 = sbase[b2];
            int nm = n1 > n2 ? n1 : n2;
            for (int i = l16; i < nm; i += 16) {
                float v1 = 0.0f, v2 = 0.0f;
                bool q1 = i < n1, q2 = i < n2;
                if (q1) v1 = nvf[src1 + i];
                if (q2) v2 = nvf[src2 + i];
                if (q1) ldsv[st1 + i] = v1;
                if (q2) ldsv[st2 + i] = v2;
            }
        }
    }
    __syncthreads();
    const unsigned long long* sl8 = reinterpret_cast<const unsigned long long*>(slotLocal)
                                    + (size_t)chunk * CV4;
    v4f* o4 = reinterpret_cast<v4f*>(out) + (size_t)chunk * CV4;
    #pragma unroll
    for (int t = 0; t < CV4/1024; ++t) {
        unsigned long long pk = __builtin_nontemporal_load(sl8 + t*1024 + tid);
        v4f o;
        o.x = ldsv[pk & 0xFFFF];
        o.y = ldsv[(pk >> 16) & 0xFFFF];
        o.z = ldsv[(pk >> 32) & 0xFFFF];
        o.w = ldsv[(pk >> 48) & 0xFFFF];
        o4[t*1024 + tid] = o;                // coalesced pixel-order write
    }
}

// ---------------- fallback: direct pixel gather -------------------------------
__global__ void k_pixel_gather(const float* __restrict__ cum,
                               const int* __restrict__ ptn,
                               float* __restrict__ out, int M) {
    int t = blockIdx.x * blockDim.x + threadIdx.x;
    int base = t * 4;
    if (base + 3 < M) {
        v4i idx = __builtin_nontemporal_load(reinterpret_cast<const v4i*>(ptn) + t);
        float4 o;
        o.x = cum[idx.x]; o.y = cum[idx.y]; o.z = cum[idx.z]; o.w = cum[idx.w];
        reinterpret_cast<float4*>(out)[t] = o;
    } else {
        for (int p = base; p < M; ++p) out[p] = cum[ptn[p]];
    }
}

extern "C" void kernel_launch(void* const* d_in, const int* in_sizes, int n_in,
                              void* d_out, int out_size, void* d_ws, size_t ws_size,
                              hipStream_t stream) {
    const float* attrs   = (const float*)d_in[0];
    const float* weight  = (const float*)d_in[1];
    const float* bias    = (const float*)d_in[2];
    const float* residue = (const float*)d_in[3];
    const int*   parent  = (const int*)d_in[4];
    const int*   ptn     = (const int*)d_in[5];
    float* out = (float*)d_out;

    const int N  = in_sizes[3];
    const int HW = in_sizes[5];
    const int BLK = 256;

    int shift = 0;
    while (((long)(N - 1) >> shift) >= NB) ++shift;
    int nBins = (int)(((long)(N - 1) >> shift) + 1);

    const int nChunks = HW / CHUNK_PX;
    const int nGroups = nChunks / 32;
    const int q8 = (nChunks % 8 == 0) ? nChunks / 8 : 0;

    auto align256 = [](size_t x) { return (x + 255) & ~(size_t)255; };
    const size_t cumB   = align256((size_t)(N + 1) * 4);
    const size_t pkB    = (size_t)(N + 1) * 8;
    const size_t slB    = (size_t)HW * 2;
    const size_t regA   = align256(pkB > slB ? pkB : slB);   // packed / slotLocal alias
    const size_t nvB    = align256(((size_t)HW + (size_t)NB*64) * 4);
    const size_t wcntB  = align256((size_t)nChunks * NB * 2);
    const size_t PB     = align256((size_t)nGroups * NB * 4);
    const size_t basesB = align256((size_t)nChunks * NB * 4);
    const size_t need   = cumB + regA + nvB + wcntB + PB + basesB + 4096;

    float* cum    = (float*)d_ws;
    int2*  packed = (int2*)((char*)d_ws + cumB);
    unsigned short* slotLocal = (unsigned short*)((char*)d_ws + cumB);  // alias (packed dead)
    int*   nv     = (int*)((char*)d_ws + cumB + regA);
    unsigned short* wcnt = (unsigned short*)((char*)d_ws + cumB + regA + nvB);
    int*   P      = (int*)((char*)d_ws + cumB + regA + nvB + wcntB);
    int*   bases  = (int*)((char*)d_ws + cumB + regA + nvB + wcntB + PB);
    int*   binStart = (int*)((char*)d_ws + cumB + regA + nvB + wcntB + PB + basesB);
    int*   binCnt   = binStart + NB;

    bool binnedOK = (HW % CHUNK_PX == 0) && (nChunks % 32 == 0) && (nChunks >= 32) &&
                    (shift <= 13) && (ws_size >= need) && (N >= 2);

    // A) gate+pack | count
    int g1 = (N + 1 + BLK - 1) / BLK;
    int gC = binnedOK ? nChunks : 0;
    k_gate_count512<<<g1 + gC, BLK, 0, stream>>>(attrs, weight, bias, residue,
                                                 parent, packed, N,
                                                 ptn, wcnt, shift, g1);

    if (binnedOK) {
        k_scanA<<<nGroups, 512, 0, stream>>>(wcnt, P);
        k_scanB<<<1, 512, 0, stream>>>(P, binStart, binCnt, nGroups);
        k_scanC<<<nGroups, 512, 0, stream>>>(wcnt, P, binStart, bases);
    }

    // walks: cutoffs 16K / 256K / 1M / N
    int c0 = 16384;   if (c0 > N) c0 = N;
    int c1 = 262144;  if (c1 > N) c1 = N;
    int c2 = 1048576; if (c2 > N) c2 = N;

    k_walk_lvl0<<<(c0 + BLK - 1) / BLK, BLK, 0, stream>>>(packed, cum, c0, N);
    if (c1 > c0) {
        int n1 = c1 - c0;
        k_walk_lvl4<<<(n1 + 4*BLK - 1) / (4*BLK), BLK, 0, stream>>>(packed, cum, c0, c1, c0);
    }
    if (c2 > c1) {
        int n2 = c2 - c1;
        k_walk_lvl4<<<(n2 + 4*BLK - 1) / (4*BLK), BLK, 0, stream>>>(packed, cum, c1, c2, c1);
    }
    if (N > c2) {
        int n3 = N - c2;
        k_walk_lvl4<<<(n3 + 4*BLK - 1) / (4*BLK), BLK, 0, stream>>>(packed, cum, c2, N, c2);
    }

    if (binnedOK) {
        // packed is dead from here on; slotLocal reuses its region
        k_scatter512<<<nChunks, 1024, 0, stream>>>(ptn, wcnt, bases, nv, slotLocal,
                                                   shift, q8);
        k_gather512<<<nBins, 512, 0, stream>>>(nv, cum, binStart, binCnt, shift, N);
        k_merge512<<<nChunks, 1024, 0, stream>>>(wcnt, bases, (const float*)nv,
                                                 slotLocal, out, q8);
    } else {
        int nQuads = (HW + 3) / 4;
        k_pixel_gather<<<(nQuads + BLK - 1) / BLK, BLK, 0, stream>>>(cum, ptn, out, HW);
    }
}